// Round 2
// baseline (1601.589 us; speedup 1.0000x reference)
//
#include <hip/hip_runtime.h>

#define NS   125      // n_support
#define NW   5        // n_way
#define NQ   2048
#define DD   8192
#define CREG 0.1f
#define PGD_ITERS 10

// ws float offsets
#define OFF_K     1000000              // 15625 floats (K), atomically accumulated
#define OFF_FLAGS 1015632              // 3 u32 flags (zeroed by memset with K)
#define OFF_QP3   1016000              // 625
#define OFF_W     1017000              // 5*8192

#define NBLK      512
#define GRAM_BLKS 256
#define W_BLKS    128

// Single normal-launch kernel, self-synced via workspace flags.
// Occupancy: 69,644 B LDS -> 2 blocks/CU; __launch_bounds__(256,2) caps VGPR<=256
// => 512 blocks ALL co-resident => flag waits are deadlock-free.
// Coherence: producers syncthreads (vmcnt drain) + __threadfence (agent wbl2/inv)
// + RELEASE atomic; consumers ACQUIRE atomic spin + __threadfence, then plain loads.
// K is built with device-scope atomicAdd (coherent at MALL) into memset-zeroed Kg.
__global__ __launch_bounds__(256, 2) void mega(
        const float* __restrict__ query,
        const float* __restrict__ support,
        const int*   __restrict__ labels,
        const float* __restrict__ scale,
        float* __restrict__ Kg,
        unsigned int* __restrict__ flags,
        float* __restrict__ qp3,
        float* __restrict__ W,
        float* __restrict__ out)
{
    __shared__ __align__(16) float sm[17408];   // 69,632 B (gram tiles = max phase)
    __shared__ float rsx[2];
    __shared__ int   svc;

    const int tid = threadIdx.x;
    const int bid = blockIdx.x;
    const float4* q4 = (const float4*)query;

    // ================= Phase G: gram (blocks 0..255) || prefetch (256..511) =========
    if (bid < GRAM_BLKS) {
        float (*As)[68] = (float (*)[68])sm;            // [128][68], pitch 68
        float (*Bs)[68] = (float (*)[68])(sm + 8704);
        const int c  = bid >> 2;
        const int qy = (bid >> 1) & 1, qz = bid & 1;
        const int d0 = c * 128;
        const int sy0 = qy * 64, sz0 = qz * 64;
        for (int idx = tid; idx < 64 * 128; idx += 256) {
            int sl = idx >> 7, dj = idx & 127;
            int sa = sy0 + sl, sb = sz0 + sl;
            As[dj][sl] = (sa < NS) ? support[(size_t)sa * DD + d0 + dj] : 0.f;
            Bs[dj][sl] = (sb < NS) ? support[(size_t)sb * DD + d0 + dj] : 0.f;
        }
        __syncthreads();
        const int tx = tid & 15, ty = tid >> 4;
        float acc[4][4];
#pragma unroll
        for (int i = 0; i < 4; i++)
#pragma unroll
            for (int j = 0; j < 4; j++) acc[i][j] = 0.f;
#pragma unroll 4
        for (int d = 0; d < 128; ++d) {
            float4 a = *(const float4*)&As[d][tx * 4];
            float4 b = *(const float4*)&Bs[d][ty * 4];
            float av[4] = {a.x, a.y, a.z, a.w};
            float bv[4] = {b.x, b.y, b.z, b.w};
#pragma unroll
            for (int i = 0; i < 4; i++)
#pragma unroll
                for (int j = 0; j < 4; j++) acc[i][j] += av[i] * bv[j];
        }
        // accumulate directly into Kg (device-scope atomics -> coherent)
#pragma unroll
        for (int i = 0; i < 4; i++) {
            int gi = sy0 + tx * 4 + i;
            if (gi >= NS) continue;
#pragma unroll
            for (int j = 0; j < 4; j++) {
                int gj = sz0 + ty * 4 + j;
                if (gj < NS) atomicAdd(&Kg[gi * NS + gj], acc[i][j]);
            }
        }
        __syncthreads();   // drain all lanes' atomics (vmcnt) before signaling
        if (tid == 0) {
            __threadfence();
            __hip_atomic_fetch_add(&flags[0], 1u, __ATOMIC_RELEASE, __HIP_MEMORY_SCOPE_AGENT);
        }
    } else {
        // prefetch queries q[(bid-256)*8 .. +8) into L3 during gram+QP window
        size_t base = (size_t)(bid - 256) * 8 * (DD / 4);
        float acc = 0.f;
        for (int k = 0; k < 64; ++k) {
            float4 v = q4[base + (size_t)k * 256 + tid];
            acc += v.x + v.y + v.z + v.w;
        }
        asm volatile("" :: "v"(acc));   // keep loads alive
    }

    // ================= Phase QP: block 0 only =================
    if (bid == 0) {
        while (__hip_atomic_load(&flags[0], __ATOMIC_ACQUIRE, __HIP_MEMORY_SCOPE_AGENT) < (unsigned)GRAM_BLKS)
            __builtin_amdgcn_s_sleep(4);
        __threadfence();   // invalidate local caches -> fresh Kg

        float* red2 = sm;          // [2][128*25] : p*3200 + r*25 + w*5 + a
        float* zsw  = sm + 6400;   // [2][4][NW][32] : p*640 + w*160 + a*32 + j
        const int w    = tid >> 6;
        const int lane = tid & 63;
        const int c0   = w * 32;
        const int r0 = lane, r1 = lane + 64;
        float kr0[32], kr1[32];
#pragma unroll
        for (int j = 0; j < 32; ++j) {
            const int col = c0 + j;
            const bool cv = (col < NS);
            kr0[j] = cv ? Kg[col * NS + r0] : 0.f;
            kr1[j] = (cv && r1 < NS) ? Kg[col * NS + r1] : 0.f;
        }
        for (int idx = tid; idx < 2 * 4 * NW * 32; idx += 256) zsw[idx] = 0.f;
        if (tid == 0) svc = 0;
        float rsum0 = 0.f, rsum1 = 0.f;
#pragma unroll
        for (int j = 0; j < 32; ++j) { rsum0 += fabsf(kr0[j]); rsum1 += fabsf(kr1[j]); }
        red2[r0 * 25 + w * 5] = rsum0;
        red2[r1 * 25 + w * 5] = rsum1;
        __syncthreads();
        const int prw = w * 64 + lane;
        if (w < 2) {
            const float* rr = &red2[prw * 25];
            float t = (prw < NS) ? rr[0] + rr[5] + rr[10] + rr[15] : 0.f;
#pragma unroll
            for (int off = 32; off; off >>= 1) t = fmaxf(t, __shfl_xor(t, off));
            if (lane == 0) rsx[w] = t;
        }
        __syncthreads();
        const float eta = 1.9f / (fmaxf(rsx[0], rsx[1]) + 1.0f);  // G = kron(K,I5)+I
        const int pr  = c0 + lane;
        const bool act = (lane < 32) && (pr < NS);
        const int lab = act ? labels[pr] : 0;
        float z[NW] = {0.f, 0.f, 0.f, 0.f, 0.f};

        for (int it = 0; it < PGD_ITERS; ++it) {
            const int p = it & 1, n = p ^ 1;
            float acc0[NW] = {0.f, 0.f, 0.f, 0.f, 0.f};
            float acc1[NW] = {0.f, 0.f, 0.f, 0.f, 0.f};
            const float* zb = zsw + p * 640 + w * 160;
#pragma unroll
            for (int c = 0; c < 8; ++c) {
                float4 z0 = *(const float4*)&zb[0 * 32 + 4 * c];
                float4 z1 = *(const float4*)&zb[1 * 32 + 4 * c];
                float4 z2 = *(const float4*)&zb[2 * 32 + 4 * c];
                float4 z3 = *(const float4*)&zb[3 * 32 + 4 * c];
                float4 z4 = *(const float4*)&zb[4 * 32 + 4 * c];
                const float k00 = kr0[4*c], k01 = kr0[4*c+1], k02 = kr0[4*c+2], k03 = kr0[4*c+3];
                const float k10 = kr1[4*c], k11 = kr1[4*c+1], k12 = kr1[4*c+2], k13 = kr1[4*c+3];
                acc0[0] += k00*z0.x + k01*z0.y + k02*z0.z + k03*z0.w;
                acc0[1] += k00*z1.x + k01*z1.y + k02*z1.z + k03*z1.w;
                acc0[2] += k00*z2.x + k01*z2.y + k02*z2.z + k03*z2.w;
                acc0[3] += k00*z3.x + k01*z3.y + k02*z3.z + k03*z3.w;
                acc0[4] += k00*z4.x + k01*z4.y + k02*z4.z + k03*z4.w;
                acc1[0] += k10*z0.x + k11*z0.y + k12*z0.z + k13*z0.w;
                acc1[1] += k10*z1.x + k11*z1.y + k12*z1.z + k13*z1.w;
                acc1[2] += k10*z2.x + k11*z2.y + k12*z2.z + k13*z2.w;
                acc1[3] += k10*z3.x + k11*z3.y + k12*z3.z + k13*z3.w;
                acc1[4] += k10*z4.x + k11*z4.y + k12*z4.z + k13*z4.w;
            }
            {
                float* b0 = &red2[p * 3200 + r0 * 25 + w * 5];
                b0[0] = acc0[0]; b0[1] = acc0[1]; b0[2] = acc0[2]; b0[3] = acc0[3]; b0[4] = acc0[4];
                float* b1 = &red2[p * 3200 + r1 * 25 + w * 5];
                b1[0] = acc1[0]; b1[1] = acc1[1]; b1[2] = acc1[2]; b1[3] = acc1[3]; b1[4] = acc1[4];
            }
            __syncthreads();
            if (act) {
                const float* rr = &red2[p * 3200 + pr * 25];
                float v[NW], h[NW];
#pragma unroll
                for (int a = 0; a < NW; a++) {
                    float kz = rr[a] + rr[5 + a] + rr[10 + a] + rr[15 + a];
                    float g = kz + z[a] - ((a == lab) ? 1.f : 0.f);   // Gz + e
                    v[a] = z[a] - eta * g;
                    h[a] = (a == lab) ? CREG : 0.f;
                }
                float tau = fmaxf(fmaxf(fmaxf(v[0], v[1]), fmaxf(v[2], v[3])), v[4]);
#pragma unroll
                for (int nn = 0; nn < 7; ++nn) {
                    float g = 0.f, nf = 0.f;
#pragma unroll
                    for (int a = 0; a < NW; a++) {
                        float d = v[a] - tau;
                        bool fr = (d <= h[a]);
                        g += fr ? d : h[a];
                        nf += fr ? 1.f : 0.f;
                    }
                    tau += g / nf;
                }
#pragma unroll
                for (int a = 0; a < NW; a++) {
                    z[a] = fminf(v[a] - tau, h[a]);
                    zsw[n * 640 + w * 160 + a * 32 + lane] = z[a];
                }
            }
        }

        if (act) {
            float m = fmaxf(fmaxf(fmaxf(z[0], z[1]), fmaxf(z[2], z[3])), z[4]);
            if (m > 0.001f) atomicAdd(&svc, 1);
#pragma unroll
            for (int a = 0; a < NW; a++) qp3[pr * NW + a] = z[a];
        }
        __syncthreads();   // drain qp3 stores + svc
        if (tid == 0) {
            out[NQ * NW] = (float)svc;
            __threadfence();
            __hip_atomic_fetch_add(&flags[1], 1u, __ATOMIC_RELEASE, __HIP_MEMORY_SCOPE_AGENT);
        }
    } else if (bid < W_BLKS) {
        while (__hip_atomic_load(&flags[1], __ATOMIC_ACQUIRE, __HIP_MEMORY_SCOPE_AGENT) < 1u)
            __builtin_amdgcn_s_sleep(4);
        __threadfence();   // fresh qp3
    }

    // ================= Phase W: blocks 0..127 =================
    if (bid < W_BLKS) {
        __syncthreads();           // LDS WAR vs gram/QP
        float* q3  = sm;           // 625
        float* red = sm + 640;     // 4*64*NW = 5120
        for (int i = tid; i < NS * NW; i += 256) q3[i] = qp3[i];
        __syncthreads();
        const int ld = tid & 63;
        const int sq = tid >> 6;
        const int d  = bid * 64 + ld;
        const int s0 = sq * 32;
        const int s1 = (sq == 3) ? NS : (s0 + 32);
        float acc[NW] = {0.f, 0.f, 0.f, 0.f, 0.f};
#pragma unroll 4
        for (int s = s0; s < s1; ++s) {
            float sv = support[(size_t)s * DD + d];
#pragma unroll
            for (int a = 0; a < NW; a++) acc[a] += sv * q3[s * NW + a];
        }
        float* rr = &red[tid * NW];
#pragma unroll
        for (int a = 0; a < NW; a++) rr[a] = acc[a];
        __syncthreads();
        if (sq == 0) {
#pragma unroll
            for (int a = 0; a < NW; a++) {
                float s = red[(0 * 64 + ld) * NW + a] + red[(1 * 64 + ld) * NW + a]
                        + red[(2 * 64 + ld) * NW + a] + red[(3 * 64 + ld) * NW + a];
                W[(size_t)a * DD + d] = s;
            }
        }
        __syncthreads();           // drain W stores before signaling
        if (tid == 0) {
            __threadfence();
            __hip_atomic_fetch_add(&flags[2], 1u, __ATOMIC_RELEASE, __HIP_MEMORY_SCOPE_AGENT);
        }
    }

    // ================= wait W complete =================
    while (__hip_atomic_load(&flags[2], __ATOMIC_ACQUIRE, __HIP_MEMORY_SCOPE_AGENT) < (unsigned)W_BLKS)
        __builtin_amdgcn_s_sleep(4);
    __threadfence();   // fresh W

    // ================= Phase L: logits, 4 queries/block (2 reps x 2q) =============
    {
        float (*red)[2][NW] = (float (*)[2][NW])sm;    // [4][2][NW]
        const int wave = tid >> 6, lane = tid & 63;
        const int v0 = wave * 512;             // wave's float4 base (2048 floats)
        const float4* W4 = (const float4*)W;
        const float sc = scale[0];
        for (int rep = 0; rep < 2; ++rep) {
            __syncthreads();                   // LDS WAR (phase W / previous rep)
            const int q0 = bid * 4 + rep * 2;
            float a0[NW] = {0.f,0.f,0.f,0.f,0.f};
            float a1[NW] = {0.f,0.f,0.f,0.f,0.f};
            const float4* qp0 = (const float4*)(query + (size_t)q0 * DD);
            const float4* qp1 = (const float4*)(query + (size_t)(q0 + 1) * DD);
#pragma unroll 2
            for (int it = 0; it < 8; ++it) {
                int dv = v0 + it * 64 + lane;
                float4 qv0 = qp0[dv];
                float4 qv1 = qp1[dv];
#pragma unroll
                for (int a = 0; a < NW; a++) {
                    float4 wv = W4[a * (DD / 4) + dv];
                    a0[a] += qv0.x*wv.x + qv0.y*wv.y + qv0.z*wv.z + qv0.w*wv.w;
                    a1[a] += qv1.x*wv.x + qv1.y*wv.y + qv1.z*wv.z + qv1.w*wv.w;
                }
            }
#pragma unroll
            for (int off = 32; off; off >>= 1) {
#pragma unroll
                for (int a = 0; a < NW; a++) {
                    a0[a] += __shfl_xor(a0[a], off);
                    a1[a] += __shfl_xor(a1[a], off);
                }
            }
            if (lane == 0) {
#pragma unroll
                for (int a = 0; a < NW; a++) { red[wave][0][a] = a0[a]; red[wave][1][a] = a1[a]; }
            }
            __syncthreads();
            if (tid < 2 * NW) {
                const int ql = tid / NW, a = tid % NW;
                float s = red[0][ql][a] + red[1][ql][a] + red[2][ql][a] + red[3][ql][a];
                out[(q0 + ql) * NW + a] = sc * s;
            }
        }
    }
}

extern "C" void kernel_launch(void* const* d_in, const int* in_sizes, int n_in,
                              void* d_out, int out_size, void* d_ws, size_t ws_size,
                              hipStream_t stream) {
    const float* query   = (const float*)d_in[0];
    const float* support = (const float*)d_in[1];
    const int*   labels  = (const int*)d_in[2];
    const float* scale   = (const float*)d_in[5];
    float* out = (float*)d_out;
    float* ws  = (float*)d_ws;

    float* Kg            = ws + OFF_K;
    unsigned int* flags  = (unsigned int*)(ws + OFF_FLAGS);
    float* qp3           = ws + OFF_QP3;
    float* W             = ws + OFF_W;

    // zero K accumulator + flags (covers OFF_K .. OFF_FLAGS+3)
    hipMemsetAsync((void*)Kg, 0, (size_t)(OFF_FLAGS + 16 - OFF_K) * sizeof(float), stream);

    hipLaunchKernelGGL(mega, dim3(NBLK), dim3(256), 0, stream,
                       query, support, labels, scale, Kg, flags, qp3, W, out);
}

// Round 3
// 270.154 us; speedup vs baseline: 5.9284x; 5.9284x over previous
//
#include <hip/hip_runtime.h>

#define NS   125      // n_support
#define NW   5        // n_way
#define NQ   2048
#define DD   8192
#define CREG 0.1f
#define PGD_ITERS 10

// ws float offsets
#define OFF_K     1000000              // 15625 floats (K), atomically accumulated
#define OFF_FLAGS 1015632              // 3 u32 flags (zeroed by memset with K)
#define OFF_QP3   1016000              // 625
#define OFF_W     1017000              // 5*8192

#define NBLK      512
#define GRAM_BLKS 256
#define W_BLKS    128

// Single normal-launch kernel, self-synced via workspace flags.
// Occupancy: 69,644 B LDS -> 2 blocks/CU; __launch_bounds__(256,2) caps VGPR<=256
// => 512 blocks ALL co-resident => flag waits are deadlock-free.
//
// Sync idiom (round-3 fix): ONE relaxed spinner per block (no per-poll cache
// invalidate), then __syncthreads + a SINGLE acquire load per thread (one
// buffer_inv per wave, once per phase). Producers: __syncthreads (vmcnt drain)
// + RELEASE fetch_add (emits L2 writeback on gfx940+).
__global__ __launch_bounds__(256, 2) void mega(
        const float* __restrict__ query,
        const float* __restrict__ support,
        const int*   __restrict__ labels,
        const float* __restrict__ scale,
        float* __restrict__ Kg,
        unsigned int* __restrict__ flags,
        float* __restrict__ qp3,
        float* __restrict__ W,
        float* __restrict__ out)
{
    __shared__ __align__(16) float sm[17408];   // 69,632 B (gram tiles = max phase)
    __shared__ float rsx[2];
    __shared__ int   svc;

    const int tid = threadIdx.x;
    const int bid = blockIdx.x;
    const float4* q4 = (const float4*)query;

    // ================= Phase G: gram (blocks 0..255) || prefetch (256..511) =========
    if (bid < GRAM_BLKS) {
        float (*As)[68] = (float (*)[68])sm;            // [128][68], pitch 68
        float (*Bs)[68] = (float (*)[68])(sm + 8704);
        const int c  = bid >> 2;
        const int qy = (bid >> 1) & 1, qz = bid & 1;
        const int d0 = c * 128;
        const int sy0 = qy * 64, sz0 = qz * 64;
        for (int idx = tid; idx < 64 * 128; idx += 256) {
            int sl = idx >> 7, dj = idx & 127;
            int sa = sy0 + sl, sb = sz0 + sl;
            As[dj][sl] = (sa < NS) ? support[(size_t)sa * DD + d0 + dj] : 0.f;
            Bs[dj][sl] = (sb < NS) ? support[(size_t)sb * DD + d0 + dj] : 0.f;
        }
        __syncthreads();
        const int tx = tid & 15, ty = tid >> 4;
        float acc[4][4];
#pragma unroll
        for (int i = 0; i < 4; i++)
#pragma unroll
            for (int j = 0; j < 4; j++) acc[i][j] = 0.f;
#pragma unroll 4
        for (int d = 0; d < 128; ++d) {
            float4 a = *(const float4*)&As[d][tx * 4];
            float4 b = *(const float4*)&Bs[d][ty * 4];
            float av[4] = {a.x, a.y, a.z, a.w};
            float bv[4] = {b.x, b.y, b.z, b.w};
#pragma unroll
            for (int i = 0; i < 4; i++)
#pragma unroll
                for (int j = 0; j < 4; j++) acc[i][j] += av[i] * bv[j];
        }
        // accumulate directly into Kg (device-scope atomics -> coherent at MALL)
#pragma unroll
        for (int i = 0; i < 4; i++) {
            int gi = sy0 + tx * 4 + i;
            if (gi >= NS) continue;
#pragma unroll
            for (int j = 0; j < 4; j++) {
                int gj = sz0 + ty * 4 + j;
                if (gj < NS) atomicAdd(&Kg[gi * NS + gj], acc[i][j]);
            }
        }
        __syncthreads();   // drain all lanes' atomics (vmcnt) before signaling
        if (tid == 0)
            __hip_atomic_fetch_add(&flags[0], 1u, __ATOMIC_RELEASE, __HIP_MEMORY_SCOPE_AGENT);
    } else {
        // prefetch queries q[(bid-256)*8 .. +8) into L3 during gram+QP window
        size_t base = (size_t)(bid - 256) * 8 * (DD / 4);
        float acc = 0.f;
        for (int k = 0; k < 64; ++k) {
            float4 v = q4[base + (size_t)k * 256 + tid];
            acc += v.x + v.y + v.z + v.w;
        }
        asm volatile("" :: "v"(acc));   // keep loads alive
    }

    // ================= Phase QP: block 0 only =================
    if (bid == 0) {
        if (tid == 0) {
            while (__hip_atomic_load(&flags[0], __ATOMIC_RELAXED, __HIP_MEMORY_SCOPE_AGENT) < (unsigned)GRAM_BLKS)
                __builtin_amdgcn_s_sleep(8);
        }
        __syncthreads();
        // one acquire per thread (one buffer_inv per wave) -> fresh Kg
        (void)__hip_atomic_load(&flags[0], __ATOMIC_ACQUIRE, __HIP_MEMORY_SCOPE_AGENT);

        float* red2 = sm;          // [2][128*25] : p*3200 + r*25 + w*5 + a
        float* zsw  = sm + 6400;   // [2][4][NW][32] : p*640 + w*160 + a*32 + j
        const int w    = tid >> 6;
        const int lane = tid & 63;
        const int c0   = w * 32;
        const int r0 = lane, r1 = lane + 64;
        float kr0[32], kr1[32];
#pragma unroll
        for (int j = 0; j < 32; ++j) {
            const int col = c0 + j;
            const bool cv = (col < NS);
            kr0[j] = cv ? Kg[col * NS + r0] : 0.f;
            kr1[j] = (cv && r1 < NS) ? Kg[col * NS + r1] : 0.f;
        }
        for (int idx = tid; idx < 2 * 4 * NW * 32; idx += 256) zsw[idx] = 0.f;
        if (tid == 0) svc = 0;
        float rsum0 = 0.f, rsum1 = 0.f;
#pragma unroll
        for (int j = 0; j < 32; ++j) { rsum0 += fabsf(kr0[j]); rsum1 += fabsf(kr1[j]); }
        red2[r0 * 25 + w * 5] = rsum0;
        red2[r1 * 25 + w * 5] = rsum1;
        __syncthreads();
        const int prw = w * 64 + lane;
        if (w < 2) {
            const float* rr = &red2[prw * 25];
            float t = (prw < NS) ? rr[0] + rr[5] + rr[10] + rr[15] : 0.f;
#pragma unroll
            for (int off = 32; off; off >>= 1) t = fmaxf(t, __shfl_xor(t, off));
            if (lane == 0) rsx[w] = t;
        }
        __syncthreads();
        const float eta = 1.9f / (fmaxf(rsx[0], rsx[1]) + 1.0f);  // G = kron(K,I5)+I
        const int pr  = c0 + lane;
        const bool act = (lane < 32) && (pr < NS);
        const int lab = act ? labels[pr] : 0;
        float z[NW] = {0.f, 0.f, 0.f, 0.f, 0.f};

        for (int it = 0; it < PGD_ITERS; ++it) {
            const int p = it & 1, n = p ^ 1;
            float acc0[NW] = {0.f, 0.f, 0.f, 0.f, 0.f};
            float acc1[NW] = {0.f, 0.f, 0.f, 0.f, 0.f};
            const float* zb = zsw + p * 640 + w * 160;
#pragma unroll
            for (int c = 0; c < 8; ++c) {
                float4 z0 = *(const float4*)&zb[0 * 32 + 4 * c];
                float4 z1 = *(const float4*)&zb[1 * 32 + 4 * c];
                float4 z2 = *(const float4*)&zb[2 * 32 + 4 * c];
                float4 z3 = *(const float4*)&zb[3 * 32 + 4 * c];
                float4 z4 = *(const float4*)&zb[4 * 32 + 4 * c];
                const float k00 = kr0[4*c], k01 = kr0[4*c+1], k02 = kr0[4*c+2], k03 = kr0[4*c+3];
                const float k10 = kr1[4*c], k11 = kr1[4*c+1], k12 = kr1[4*c+2], k13 = kr1[4*c+3];
                acc0[0] += k00*z0.x + k01*z0.y + k02*z0.z + k03*z0.w;
                acc0[1] += k00*z1.x + k01*z1.y + k02*z1.z + k03*z1.w;
                acc0[2] += k00*z2.x + k01*z2.y + k02*z2.z + k03*z2.w;
                acc0[3] += k00*z3.x + k01*z3.y + k02*z3.z + k03*z3.w;
                acc0[4] += k00*z4.x + k01*z4.y + k02*z4.z + k03*z4.w;
                acc1[0] += k10*z0.x + k11*z0.y + k12*z0.z + k13*z0.w;
                acc1[1] += k10*z1.x + k11*z1.y + k12*z1.z + k13*z1.w;
                acc1[2] += k10*z2.x + k11*z2.y + k12*z2.z + k13*z2.w;
                acc1[3] += k10*z3.x + k11*z3.y + k12*z3.z + k13*z3.w;
                acc1[4] += k10*z4.x + k11*z4.y + k12*z4.z + k13*z4.w;
            }
            {
                float* b0 = &red2[p * 3200 + r0 * 25 + w * 5];
                b0[0] = acc0[0]; b0[1] = acc0[1]; b0[2] = acc0[2]; b0[3] = acc0[3]; b0[4] = acc0[4];
                float* b1 = &red2[p * 3200 + r1 * 25 + w * 5];
                b1[0] = acc1[0]; b1[1] = acc1[1]; b1[2] = acc1[2]; b1[3] = acc1[3]; b1[4] = acc1[4];
            }
            __syncthreads();
            if (act) {
                const float* rr = &red2[p * 3200 + pr * 25];
                float v[NW], h[NW];
#pragma unroll
                for (int a = 0; a < NW; a++) {
                    float kz = rr[a] + rr[5 + a] + rr[10 + a] + rr[15 + a];
                    float g = kz + z[a] - ((a == lab) ? 1.f : 0.f);   // Gz + e
                    v[a] = z[a] - eta * g;
                    h[a] = (a == lab) ? CREG : 0.f;
                }
                float tau = fmaxf(fmaxf(fmaxf(v[0], v[1]), fmaxf(v[2], v[3])), v[4]);
#pragma unroll
                for (int nn = 0; nn < 7; ++nn) {
                    float g = 0.f, nf = 0.f;
#pragma unroll
                    for (int a = 0; a < NW; a++) {
                        float d = v[a] - tau;
                        bool fr = (d <= h[a]);
                        g += fr ? d : h[a];
                        nf += fr ? 1.f : 0.f;
                    }
                    tau += g / nf;
                }
#pragma unroll
                for (int a = 0; a < NW; a++) {
                    z[a] = fminf(v[a] - tau, h[a]);
                    zsw[n * 640 + w * 160 + a * 32 + lane] = z[a];
                }
            }
        }

        if (act) {
            float m = fmaxf(fmaxf(fmaxf(z[0], z[1]), fmaxf(z[2], z[3])), z[4]);
            if (m > 0.001f) atomicAdd(&svc, 1);
#pragma unroll
            for (int a = 0; a < NW; a++) qp3[pr * NW + a] = z[a];
        }
        __syncthreads();   // drain qp3 stores + svc
        if (tid == 0) {
            out[NQ * NW] = (float)svc;
            __hip_atomic_fetch_add(&flags[1], 1u, __ATOMIC_RELEASE, __HIP_MEMORY_SCOPE_AGENT);
        }
    } else if (bid < W_BLKS) {
        if (tid == 0) {
            while (__hip_atomic_load(&flags[1], __ATOMIC_RELAXED, __HIP_MEMORY_SCOPE_AGENT) < 1u)
                __builtin_amdgcn_s_sleep(8);
        }
        __syncthreads();
        (void)__hip_atomic_load(&flags[1], __ATOMIC_ACQUIRE, __HIP_MEMORY_SCOPE_AGENT);  // fresh qp3
    }

    // ================= Phase W: blocks 0..127 =================
    if (bid < W_BLKS) {
        __syncthreads();           // LDS WAR vs gram/QP
        float* q3  = sm;           // 625
        float* red = sm + 640;     // 4*64*NW = 5120
        for (int i = tid; i < NS * NW; i += 256) q3[i] = qp3[i];
        __syncthreads();
        const int ld = tid & 63;
        const int sq = tid >> 6;
        const int d  = bid * 64 + ld;
        const int s0 = sq * 32;
        const int s1 = (sq == 3) ? NS : (s0 + 32);
        float acc[NW] = {0.f, 0.f, 0.f, 0.f, 0.f};
#pragma unroll 4
        for (int s = s0; s < s1; ++s) {
            float sv = support[(size_t)s * DD + d];
#pragma unroll
            for (int a = 0; a < NW; a++) acc[a] += sv * q3[s * NW + a];
        }
        float* rr = &red[tid * NW];
#pragma unroll
        for (int a = 0; a < NW; a++) rr[a] = acc[a];
        __syncthreads();
        if (sq == 0) {
#pragma unroll
            for (int a = 0; a < NW; a++) {
                float s = red[(0 * 64 + ld) * NW + a] + red[(1 * 64 + ld) * NW + a]
                        + red[(2 * 64 + ld) * NW + a] + red[(3 * 64 + ld) * NW + a];
                W[(size_t)a * DD + d] = s;
            }
        }
        __syncthreads();           // drain W stores before signaling
        if (tid == 0)
            __hip_atomic_fetch_add(&flags[2], 1u, __ATOMIC_RELEASE, __HIP_MEMORY_SCOPE_AGENT);
    }

    // ================= wait W complete =================
    if (tid == 0) {
        while (__hip_atomic_load(&flags[2], __ATOMIC_RELAXED, __HIP_MEMORY_SCOPE_AGENT) < (unsigned)W_BLKS)
            __builtin_amdgcn_s_sleep(8);
    }
    __syncthreads();
    (void)__hip_atomic_load(&flags[2], __ATOMIC_ACQUIRE, __HIP_MEMORY_SCOPE_AGENT);  // fresh W

    // ================= Phase L: logits, 4 queries/block (2 reps x 2q) =============
    {
        float (*red)[2][NW] = (float (*)[2][NW])sm;    // [4][2][NW]
        const int wave = tid >> 6, lane = tid & 63;
        const int v0 = wave * 512;             // wave's float4 base (2048 floats)
        const float4* W4 = (const float4*)W;
        const float sc = scale[0];
        for (int rep = 0; rep < 2; ++rep) {
            __syncthreads();                   // LDS WAR (phase W / previous rep)
            const int q0 = bid * 4 + rep * 2;
            float a0[NW] = {0.f,0.f,0.f,0.f,0.f};
            float a1[NW] = {0.f,0.f,0.f,0.f,0.f};
            const float4* qp0 = (const float4*)(query + (size_t)q0 * DD);
            const float4* qp1 = (const float4*)(query + (size_t)(q0 + 1) * DD);
#pragma unroll 2
            for (int it = 0; it < 8; ++it) {
                int dv = v0 + it * 64 + lane;
                float4 qv0 = qp0[dv];
                float4 qv1 = qp1[dv];
#pragma unroll
                for (int a = 0; a < NW; a++) {
                    float4 wv = W4[a * (DD / 4) + dv];
                    a0[a] += qv0.x*wv.x + qv0.y*wv.y + qv0.z*wv.z + qv0.w*wv.w;
                    a1[a] += qv1.x*wv.x + qv1.y*wv.y + qv1.z*wv.z + qv1.w*wv.w;
                }
            }
#pragma unroll
            for (int off = 32; off; off >>= 1) {
#pragma unroll
                for (int a = 0; a < NW; a++) {
                    a0[a] += __shfl_xor(a0[a], off);
                    a1[a] += __shfl_xor(a1[a], off);
                }
            }
            if (lane == 0) {
#pragma unroll
                for (int a = 0; a < NW; a++) { red[wave][0][a] = a0[a]; red[wave][1][a] = a1[a]; }
            }
            __syncthreads();
            if (tid < 2 * NW) {
                const int ql = tid / NW, a = tid % NW;
                float s = red[0][ql][a] + red[1][ql][a] + red[2][ql][a] + red[3][ql][a];
                out[(q0 + ql) * NW + a] = sc * s;
            }
        }
    }
}

extern "C" void kernel_launch(void* const* d_in, const int* in_sizes, int n_in,
                              void* d_out, int out_size, void* d_ws, size_t ws_size,
                              hipStream_t stream) {
    const float* query   = (const float*)d_in[0];
    const float* support = (const float*)d_in[1];
    const int*   labels  = (const int*)d_in[2];
    const float* scale   = (const float*)d_in[5];
    float* out = (float*)d_out;
    float* ws  = (float*)d_ws;

    float* Kg            = ws + OFF_K;
    unsigned int* flags  = (unsigned int*)(ws + OFF_FLAGS);
    float* qp3           = ws + OFF_QP3;
    float* W             = ws + OFF_W;

    // zero K accumulator + flags (covers OFF_K .. OFF_FLAGS+3)
    hipMemsetAsync((void*)Kg, 0, (size_t)(OFF_FLAGS + 16 - OFF_K) * sizeof(float), stream);

    hipLaunchKernelGGL(mega, dim3(NBLK), dim3(256), 0, stream,
                       query, support, labels, scale, Kg, flags, qp3, W, out);
}

// Round 4
// 256.299 us; speedup vs baseline: 6.2489x; 1.0541x over previous
//
#include <hip/hip_runtime.h>

#define NS   125      // n_support
#define NW   5        // n_way
#define NQ   2048
#define DD   8192
#define CREG 0.1f
#define PGD_ITERS 10

// ws float offsets
#define OFF_K     1000000              // 15625 floats (K), atomically accumulated
#define OFF_FLAGS 1015632              // flags (zeroed by memset with K)
#define OFF_QP3   1016000              // 625
#define OFF_W     1017000              // 5*8192

#define K1_BLKS   512
#define GRAM_BLKS 64                   // 4 quadrants x 16 d-groups (4 chunks each)
#define Q4_TOTAL  (NQ * (DD / 4))      // 4,194,304 float4 of query

// ================= K1: gram + prefetch + QP(block 0) =================
// blocks 0..63: gram quadrant (qy,qz), d-group of 4x128 chunks, K-loop in regs,
//               ONE atomicAdd per output element (64 blk x 16 el x 256 thr = 262K atomics).
// blocks 64..511: grid-stride prefetch of query into L2/L3 (overlaps gram + QP).
// block 0: after its gram chunk, single relaxed spinner waits for the other 63,
//          then one acquire per thread (fresh Kg) and the 10-iter PGD QP solve.
__global__ __launch_bounds__(256, 2) void k1_gram_qp(
        const float* __restrict__ query,
        const float* __restrict__ support,
        const int*   __restrict__ labels,
        float* __restrict__ Kg,
        unsigned int* __restrict__ flags,
        float* __restrict__ qp3,
        float* __restrict__ out)
{
    __shared__ __align__(16) float sm[17408];   // 69,632 B (gram tiles = max phase)
    __shared__ float rsx[2];
    __shared__ int   svc;

    const int tid = threadIdx.x;
    const int bid = blockIdx.x;

    if (bid < GRAM_BLKS) {
        // ---------- gram: 4 chunks of 128 d, accumulate in registers ----------
        float (*As)[68] = (float (*)[68])sm;            // [128][68], pitch 68
        float (*Bs)[68] = (float (*)[68])(sm + 8704);
        const int qy = bid & 1, qz = (bid >> 1) & 1;
        const int group = bid >> 2;                     // 0..15
        const int sy0 = qy * 64, sz0 = qz * 64;
        const int tx = tid & 15, ty = tid >> 4;
        float acc[4][4];
#pragma unroll
        for (int i = 0; i < 4; i++)
#pragma unroll
            for (int j = 0; j < 4; j++) acc[i][j] = 0.f;

        for (int g = 0; g < 4; ++g) {
            const int d0 = (group * 4 + g) * 128;
            if (g) __syncthreads();                     // LDS WAR vs prev compute
            for (int idx = tid; idx < 64 * 128; idx += 256) {
                int sl = idx >> 7, dj = idx & 127;
                int sa = sy0 + sl, sb = sz0 + sl;
                As[dj][sl] = (sa < NS) ? support[(size_t)sa * DD + d0 + dj] : 0.f;
                Bs[dj][sl] = (sb < NS) ? support[(size_t)sb * DD + d0 + dj] : 0.f;
            }
            __syncthreads();
#pragma unroll 4
            for (int d = 0; d < 128; ++d) {
                float4 a = *(const float4*)&As[d][tx * 4];
                float4 b = *(const float4*)&Bs[d][ty * 4];
                float av[4] = {a.x, a.y, a.z, a.w};
                float bv[4] = {b.x, b.y, b.z, b.w};
#pragma unroll
                for (int i = 0; i < 4; i++)
#pragma unroll
                    for (int j = 0; j < 4; j++) acc[i][j] += av[i] * bv[j];
            }
        }
        // one atomicAdd per output element (device-scope, coherent)
#pragma unroll
        for (int i = 0; i < 4; i++) {
            int gi = sy0 + tx * 4 + i;
            if (gi >= NS) continue;
#pragma unroll
            for (int j = 0; j < 4; j++) {
                int gj = sz0 + ty * 4 + j;
                if (gj < NS) atomicAdd(&Kg[gi * NS + gj], acc[i][j]);
            }
        }
        __syncthreads();   // drain all lanes' atomics before signaling
        if (tid == 0)
            __hip_atomic_fetch_add(&flags[0], 1u, __ATOMIC_RELEASE, __HIP_MEMORY_SCOPE_AGENT);
    } else {
        // ---------- prefetch query into L2/L3 (448 blocks, grid-stride) ----------
        const float4* q4 = (const float4*)query;
        float acc = 0.f;
        for (size_t i = (size_t)(bid - GRAM_BLKS) * 256 + tid; i < (size_t)Q4_TOTAL;
             i += (size_t)(K1_BLKS - GRAM_BLKS) * 256) {
            float4 v = q4[i];
            acc += v.x + v.y + v.z + v.w;
        }
        asm volatile("" :: "v"(acc));   // keep loads alive
    }

    if (bid != 0) return;

    // ================= QP solve (block 0 only) =================
    if (tid == 0) {
        while (__hip_atomic_load(&flags[0], __ATOMIC_RELAXED, __HIP_MEMORY_SCOPE_AGENT) < (unsigned)GRAM_BLKS)
            __builtin_amdgcn_s_sleep(8);
    }
    __syncthreads();
    // one acquire per thread (one buffer_inv per wave) -> fresh Kg
    (void)__hip_atomic_load(&flags[0], __ATOMIC_ACQUIRE, __HIP_MEMORY_SCOPE_AGENT);

    float* red2 = sm;          // [2][128*25] : p*3200 + r*25 + w*5 + a
    float* zsw  = sm + 6400;   // [2][4][NW][32] : p*640 + w*160 + a*32 + j
    const int w    = tid >> 6;
    const int lane = tid & 63;
    const int c0   = w * 32;
    const int r0 = lane, r1 = lane + 64;
    float kr0[32], kr1[32];
#pragma unroll
    for (int j = 0; j < 32; ++j) {
        const int col = c0 + j;
        const bool cv = (col < NS);
        kr0[j] = cv ? Kg[col * NS + r0] : 0.f;
        kr1[j] = (cv && r1 < NS) ? Kg[col * NS + r1] : 0.f;
    }
    for (int idx = tid; idx < 2 * 4 * NW * 32; idx += 256) zsw[idx] = 0.f;
    if (tid == 0) svc = 0;
    float rsum0 = 0.f, rsum1 = 0.f;
#pragma unroll
    for (int j = 0; j < 32; ++j) { rsum0 += fabsf(kr0[j]); rsum1 += fabsf(kr1[j]); }
    red2[r0 * 25 + w * 5] = rsum0;
    red2[r1 * 25 + w * 5] = rsum1;
    __syncthreads();
    const int prw = w * 64 + lane;
    if (w < 2) {
        const float* rr = &red2[prw * 25];
        float t = (prw < NS) ? rr[0] + rr[5] + rr[10] + rr[15] : 0.f;
#pragma unroll
        for (int off = 32; off; off >>= 1) t = fmaxf(t, __shfl_xor(t, off));
        if (lane == 0) rsx[w] = t;
    }
    __syncthreads();
    const float eta = 1.9f / (fmaxf(rsx[0], rsx[1]) + 1.0f);  // G = kron(K,I5)+I
    const int pr  = c0 + lane;
    const bool act = (lane < 32) && (pr < NS);
    const int lab = act ? labels[pr] : 0;
    float z[NW] = {0.f, 0.f, 0.f, 0.f, 0.f};

    for (int it = 0; it < PGD_ITERS; ++it) {
        const int p = it & 1, n = p ^ 1;
        float acc0[NW] = {0.f, 0.f, 0.f, 0.f, 0.f};
        float acc1[NW] = {0.f, 0.f, 0.f, 0.f, 0.f};
        const float* zb = zsw + p * 640 + w * 160;
#pragma unroll
        for (int c = 0; c < 8; ++c) {
            float4 z0 = *(const float4*)&zb[0 * 32 + 4 * c];
            float4 z1 = *(const float4*)&zb[1 * 32 + 4 * c];
            float4 z2 = *(const float4*)&zb[2 * 32 + 4 * c];
            float4 z3 = *(const float4*)&zb[3 * 32 + 4 * c];
            float4 z4 = *(const float4*)&zb[4 * 32 + 4 * c];
            const float k00 = kr0[4*c], k01 = kr0[4*c+1], k02 = kr0[4*c+2], k03 = kr0[4*c+3];
            const float k10 = kr1[4*c], k11 = kr1[4*c+1], k12 = kr1[4*c+2], k13 = kr1[4*c+3];
            acc0[0] += k00*z0.x + k01*z0.y + k02*z0.z + k03*z0.w;
            acc0[1] += k00*z1.x + k01*z1.y + k02*z1.z + k03*z1.w;
            acc0[2] += k00*z2.x + k01*z2.y + k02*z2.z + k03*z2.w;
            acc0[3] += k00*z3.x + k01*z3.y + k02*z3.z + k03*z3.w;
            acc0[4] += k00*z4.x + k01*z4.y + k02*z4.z + k03*z4.w;
            acc1[0] += k10*z0.x + k11*z0.y + k12*z0.z + k13*z0.w;
            acc1[1] += k10*z1.x + k11*z1.y + k12*z1.z + k13*z1.w;
            acc1[2] += k10*z2.x + k11*z2.y + k12*z2.z + k13*z2.w;
            acc1[3] += k10*z3.x + k11*z3.y + k12*z3.z + k13*z3.w;
            acc1[4] += k10*z4.x + k11*z4.y + k12*z4.z + k13*z4.w;
        }
        {
            float* b0 = &red2[p * 3200 + r0 * 25 + w * 5];
            b0[0] = acc0[0]; b0[1] = acc0[1]; b0[2] = acc0[2]; b0[3] = acc0[3]; b0[4] = acc0[4];
            float* b1 = &red2[p * 3200 + r1 * 25 + w * 5];
            b1[0] = acc1[0]; b1[1] = acc1[1]; b1[2] = acc1[2]; b1[3] = acc1[3]; b1[4] = acc1[4];
        }
        __syncthreads();
        if (act) {
            const float* rr = &red2[p * 3200 + pr * 25];
            float v[NW], h[NW];
#pragma unroll
            for (int a = 0; a < NW; a++) {
                float kz = rr[a] + rr[5 + a] + rr[10 + a] + rr[15 + a];
                float g = kz + z[a] - ((a == lab) ? 1.f : 0.f);   // Gz + e
                v[a] = z[a] - eta * g;
                h[a] = (a == lab) ? CREG : 0.f;
            }
            float tau = fmaxf(fmaxf(fmaxf(v[0], v[1]), fmaxf(v[2], v[3])), v[4]);
#pragma unroll
            for (int nn = 0; nn < 7; ++nn) {
                float g = 0.f, nf = 0.f;
#pragma unroll
                for (int a = 0; a < NW; a++) {
                    float d = v[a] - tau;
                    bool fr = (d <= h[a]);
                    g += fr ? d : h[a];
                    nf += fr ? 1.f : 0.f;
                }
                tau += g / nf;
            }
#pragma unroll
            for (int a = 0; a < NW; a++) {
                z[a] = fminf(v[a] - tau, h[a]);
                zsw[n * 640 + w * 160 + a * 32 + lane] = z[a];
            }
        }
    }

    if (act) {
        float m = fmaxf(fmaxf(fmaxf(z[0], z[1]), fmaxf(z[2], z[3])), z[4]);
        if (m > 0.001f) atomicAdd(&svc, 1);
#pragma unroll
        for (int a = 0; a < NW; a++) qp3[pr * NW + a] = z[a];
    }
    __syncthreads();
    if (tid == 0) out[NQ * NW] = (float)svc;
    // kernel end = implicit release; K2 sees qp3 via dispatch boundary
}

// ================= K2: W[a][d] = sum_s support[s][d] * qp3[s][a] =================
__global__ __launch_bounds__(256) void w_kernel(const float* __restrict__ support,
                                                const float* __restrict__ qp3,
                                                float* __restrict__ W) {
    __shared__ float q3[NS * NW];
    __shared__ float red[4 * 64 * NW];
    const int tid = threadIdx.x;
    for (int i = tid; i < NS * NW; i += 256) q3[i] = qp3[i];
    __syncthreads();
    const int ld = tid & 63;
    const int sq = tid >> 6;
    const int d  = blockIdx.x * 64 + ld;
    const int s0 = sq * 32;
    const int s1 = (sq == 3) ? NS : (s0 + 32);
    float acc[NW] = {0.f, 0.f, 0.f, 0.f, 0.f};
#pragma unroll 4
    for (int s = s0; s < s1; ++s) {
        float sv = support[(size_t)s * DD + d];
#pragma unroll
        for (int a = 0; a < NW; a++) acc[a] += sv * q3[s * NW + a];
    }
    float* rr = &red[tid * NW];
#pragma unroll
    for (int a = 0; a < NW; a++) rr[a] = acc[a];
    __syncthreads();
    if (sq == 0) {
#pragma unroll
        for (int a = 0; a < NW; a++) {
            float s = red[(0 * 64 + ld) * NW + a] + red[(1 * 64 + ld) * NW + a]
                    + red[(2 * 64 + ld) * NW + a] + red[(3 * 64 + ld) * NW + a];
            W[(size_t)a * DD + d] = s;
        }
    }
}

// ================= K3: logits, 4 queries/block (2 reps x 2q), query L3-warm ======
__global__ __launch_bounds__(256) void logits_kernel(const float* __restrict__ query,
                                                     const float* __restrict__ W,
                                                     const float* __restrict__ scale,
                                                     float* __restrict__ out) {
    __shared__ float red[4][2][NW];
    const int tid = threadIdx.x;
    const int wave = tid >> 6, lane = tid & 63;
    const int v0 = wave * 512;             // wave's float4 base (2048 floats)
    const float4* W4 = (const float4*)W;
    const float sc = scale[0];
    for (int rep = 0; rep < 2; ++rep) {
        __syncthreads();                   // LDS WAR vs previous rep (no-op on rep 0)
        const int q0 = blockIdx.x * 4 + rep * 2;
        float a0[NW] = {0.f,0.f,0.f,0.f,0.f};
        float a1[NW] = {0.f,0.f,0.f,0.f,0.f};
        const float4* qp0 = (const float4*)(query + (size_t)q0 * DD);
        const float4* qp1 = (const float4*)(query + (size_t)(q0 + 1) * DD);
#pragma unroll 2
        for (int it = 0; it < 8; ++it) {
            int dv = v0 + it * 64 + lane;
            float4 qv0 = qp0[dv];
            float4 qv1 = qp1[dv];
#pragma unroll
            for (int a = 0; a < NW; a++) {
                float4 wv = W4[a * (DD / 4) + dv];
                a0[a] += qv0.x*wv.x + qv0.y*wv.y + qv0.z*wv.z + qv0.w*wv.w;
                a1[a] += qv1.x*wv.x + qv1.y*wv.y + qv1.z*wv.z + qv1.w*wv.w;
            }
        }
#pragma unroll
        for (int off = 32; off; off >>= 1) {
#pragma unroll
            for (int a = 0; a < NW; a++) {
                a0[a] += __shfl_xor(a0[a], off);
                a1[a] += __shfl_xor(a1[a], off);
            }
        }
        if (lane == 0) {
#pragma unroll
            for (int a = 0; a < NW; a++) { red[wave][0][a] = a0[a]; red[wave][1][a] = a1[a]; }
        }
        __syncthreads();
        if (tid < 2 * NW) {
            const int ql = tid / NW, a = tid % NW;
            float s = red[0][ql][a] + red[1][ql][a] + red[2][ql][a] + red[3][ql][a];
            out[(q0 + ql) * NW + a] = sc * s;
        }
    }
}

extern "C" void kernel_launch(void* const* d_in, const int* in_sizes, int n_in,
                              void* d_out, int out_size, void* d_ws, size_t ws_size,
                              hipStream_t stream) {
    const float* query   = (const float*)d_in[0];
    const float* support = (const float*)d_in[1];
    const int*   labels  = (const int*)d_in[2];
    const float* scale   = (const float*)d_in[5];
    float* out = (float*)d_out;
    float* ws  = (float*)d_ws;

    float* Kg            = ws + OFF_K;
    unsigned int* flags  = (unsigned int*)(ws + OFF_FLAGS);
    float* qp3           = ws + OFF_QP3;
    float* W             = ws + OFF_W;

    // zero K accumulator + flags (covers OFF_K .. OFF_FLAGS+16)
    hipMemsetAsync((void*)Kg, 0, (size_t)(OFF_FLAGS + 16 - OFF_K) * sizeof(float), stream);

    hipLaunchKernelGGL(k1_gram_qp, dim3(K1_BLKS), dim3(256), 0, stream,
                       query, support, labels, Kg, flags, qp3, out);
    hipLaunchKernelGGL(w_kernel, dim3(DD / 64), dim3(256), 0, stream, support, qp3, W);
    hipLaunchKernelGGL(logits_kernel, dim3(NQ / 4), dim3(256), 0, stream, query, W, scale, out);
}

// Round 5
// 222.709 us; speedup vs baseline: 7.1914x; 1.1508x over previous
//
#include <hip/hip_runtime.h>

#define NS   125      // n_support
#define NW   5        // n_way
#define NQ   2048
#define DD   8192
#define CREG 0.1f
#define PGD_ITERS 10

// ws float offsets
#define OFF_K     1000000              // 15625 floats (K), atomically accumulated
#define OFF_QP3   1016000              // 625
#define OFF_W     1017000              // 5*8192

#define K1_BLKS   512
#define GRAM_BLKS 64                   // 4 quadrants x 16 d-groups (4 chunks each)
#define Q4_TOTAL  (NQ * (DD / 4))      // 4,194,304 float4 of query

// ================= K1a: gram + query prefetch (NO cross-block sync) ==============
// blocks 0..63: gram quadrant (qy,qz), d-group of 4x128 chunks, K-loop in regs,
//               ONE atomicAdd per output element into memset-zeroed Kg.
// blocks 64..511: grid-stride prefetch of query into L2/L3 (overlaps gram; warms
//                 the 67 MB for logits two dispatches later).
__global__ __launch_bounds__(256, 2) void k1a_gram_prefetch(
        const float* __restrict__ query,
        const float* __restrict__ support,
        float* __restrict__ Kg)
{
    __shared__ __align__(16) float sm[17408];   // 69,632 B (two 128x68 tiles)

    const int tid = threadIdx.x;
    const int bid = blockIdx.x;

    if (bid < GRAM_BLKS) {
        float (*As)[68] = (float (*)[68])sm;            // [128][68], pitch 68
        float (*Bs)[68] = (float (*)[68])(sm + 8704);
        const int qy = bid & 1, qz = (bid >> 1) & 1;
        const int group = bid >> 2;                     // 0..15
        const int sy0 = qy * 64, sz0 = qz * 64;
        const int tx = tid & 15, ty = tid >> 4;
        float acc[4][4];
#pragma unroll
        for (int i = 0; i < 4; i++)
#pragma unroll
            for (int j = 0; j < 4; j++) acc[i][j] = 0.f;

        for (int g = 0; g < 4; ++g) {
            const int d0 = (group * 4 + g) * 128;
            if (g) __syncthreads();                     // LDS WAR vs prev compute
            for (int idx = tid; idx < 64 * 128; idx += 256) {
                int sl = idx >> 7, dj = idx & 127;
                int sa = sy0 + sl, sb = sz0 + sl;
                As[dj][sl] = (sa < NS) ? support[(size_t)sa * DD + d0 + dj] : 0.f;
                Bs[dj][sl] = (sb < NS) ? support[(size_t)sb * DD + d0 + dj] : 0.f;
            }
            __syncthreads();
#pragma unroll 4
            for (int d = 0; d < 128; ++d) {
                float4 a = *(const float4*)&As[d][tx * 4];
                float4 b = *(const float4*)&Bs[d][ty * 4];
                float av[4] = {a.x, a.y, a.z, a.w};
                float bv[4] = {b.x, b.y, b.z, b.w};
#pragma unroll
                for (int i = 0; i < 4; i++)
#pragma unroll
                    for (int j = 0; j < 4; j++) acc[i][j] += av[i] * bv[j];
            }
        }
        // one atomicAdd per output element (device-scope, coherent)
#pragma unroll
        for (int i = 0; i < 4; i++) {
            int gi = sy0 + tx * 4 + i;
            if (gi >= NS) continue;
#pragma unroll
            for (int j = 0; j < 4; j++) {
                int gj = sz0 + ty * 4 + j;
                if (gj < NS) atomicAdd(&Kg[gi * NS + gj], acc[i][j]);
            }
        }
    } else {
        // prefetch query into L2/L3 (448 blocks, grid-stride)
        const float4* q4 = (const float4*)query;
        float acc = 0.f;
        for (size_t i = (size_t)(bid - GRAM_BLKS) * 256 + tid; i < (size_t)Q4_TOTAL;
             i += (size_t)(K1_BLKS - GRAM_BLKS) * 256) {
            float4 v = q4[i];
            acc += v.x + v.y + v.z + v.w;
        }
        asm volatile("" :: "v"(acc));   // keep loads alive
    }
}

// ================= K1b: QP solve, 1 block (dispatch boundary syncs Kg) ===========
// Byte-identical math to the round-4 fused QP section. Own rocprof row now.
__global__ __launch_bounds__(256) void qp_solve(const float* __restrict__ Kg,
                                                const int* __restrict__ labels,
                                                float* __restrict__ qp3,
                                                float* __restrict__ outNumSv) {
    __shared__ float red2[2][128 * 25];             // [parity][row*25 + w*5 + a]
    __shared__ __align__(16) float zsw[2][4][NW][32];
    __shared__ float rsx[2];
    __shared__ int   svc;

    const int tid  = threadIdx.x;
    const int w    = tid >> 6;
    const int lane = tid & 63;
    const int c0   = w * 32;
    const int r0   = lane, r1 = lane + 64;

    float kr0[32], kr1[32];
#pragma unroll
    for (int j = 0; j < 32; ++j) {
        const int col = c0 + j;
        const bool cv = (col < NS);
        kr0[j] = cv ? Kg[col * NS + r0] : 0.f;
        kr1[j] = (cv && r1 < NS) ? Kg[col * NS + r1] : 0.f;
    }
    for (int idx = tid; idx < 2 * 4 * NW * 32; idx += 256) ((float*)zsw)[idx] = 0.f;
    if (tid == 0) svc = 0;
    float rsum0 = 0.f, rsum1 = 0.f;
#pragma unroll
    for (int j = 0; j < 32; ++j) { rsum0 += fabsf(kr0[j]); rsum1 += fabsf(kr1[j]); }
    red2[0][r0 * 25 + w * 5] = rsum0;
    red2[0][r1 * 25 + w * 5] = rsum1;
    __syncthreads();
    const int prw = w * 64 + lane;
    if (w < 2) {
        const float* rr = &red2[0][prw * 25];
        float t = (prw < NS) ? rr[0] + rr[5] + rr[10] + rr[15] : 0.f;
#pragma unroll
        for (int off = 32; off; off >>= 1) t = fmaxf(t, __shfl_xor(t, off));
        if (lane == 0) rsx[w] = t;
    }
    __syncthreads();
    const float eta = 1.9f / (fmaxf(rsx[0], rsx[1]) + 1.0f);  // G = kron(K,I5)+I
    const int pr   = c0 + lane;
    const bool act = (lane < 32) && (pr < NS);
    const int lab  = act ? labels[pr] : 0;
    float z[NW] = {0.f, 0.f, 0.f, 0.f, 0.f};

    for (int it = 0; it < PGD_ITERS; ++it) {
        const int p = it & 1, n = p ^ 1;
        float acc0[NW] = {0.f, 0.f, 0.f, 0.f, 0.f};
        float acc1[NW] = {0.f, 0.f, 0.f, 0.f, 0.f};
#pragma unroll
        for (int c = 0; c < 8; ++c) {
            float4 z0 = *(const float4*)&zsw[p][w][0][4 * c];
            float4 z1 = *(const float4*)&zsw[p][w][1][4 * c];
            float4 z2 = *(const float4*)&zsw[p][w][2][4 * c];
            float4 z3 = *(const float4*)&zsw[p][w][3][4 * c];
            float4 z4 = *(const float4*)&zsw[p][w][4][4 * c];
            const float k00 = kr0[4*c], k01 = kr0[4*c+1], k02 = kr0[4*c+2], k03 = kr0[4*c+3];
            const float k10 = kr1[4*c], k11 = kr1[4*c+1], k12 = kr1[4*c+2], k13 = kr1[4*c+3];
            acc0[0] += k00*z0.x + k01*z0.y + k02*z0.z + k03*z0.w;
            acc0[1] += k00*z1.x + k01*z1.y + k02*z1.z + k03*z1.w;
            acc0[2] += k00*z2.x + k01*z2.y + k02*z2.z + k03*z2.w;
            acc0[3] += k00*z3.x + k01*z3.y + k02*z3.z + k03*z3.w;
            acc0[4] += k00*z4.x + k01*z4.y + k02*z4.z + k03*z4.w;
            acc1[0] += k10*z0.x + k11*z0.y + k12*z0.z + k13*z0.w;
            acc1[1] += k10*z1.x + k11*z1.y + k12*z1.z + k13*z1.w;
            acc1[2] += k10*z2.x + k11*z2.y + k12*z2.z + k13*z2.w;
            acc1[3] += k10*z3.x + k11*z3.y + k12*z3.z + k13*z3.w;
            acc1[4] += k10*z4.x + k11*z4.y + k12*z4.z + k13*z4.w;
        }
        {
            float* b0 = &red2[p][r0 * 25 + w * 5];
            b0[0] = acc0[0]; b0[1] = acc0[1]; b0[2] = acc0[2]; b0[3] = acc0[3]; b0[4] = acc0[4];
            float* b1 = &red2[p][r1 * 25 + w * 5];
            b1[0] = acc1[0]; b1[1] = acc1[1]; b1[2] = acc1[2]; b1[3] = acc1[3]; b1[4] = acc1[4];
        }
        __syncthreads();                       // the ONLY barrier per iteration
        if (act) {
            const float* rr = &red2[p][pr * 25];
            float v[NW], h[NW];
#pragma unroll
            for (int a = 0; a < NW; a++) {
                float kz = rr[a] + rr[5 + a] + rr[10 + a] + rr[15 + a];
                float g = kz + z[a] - ((a == lab) ? 1.f : 0.f);   // Gz + e
                v[a] = z[a] - eta * g;
                h[a] = (a == lab) ? CREG : 0.f;
            }
            float tau = fmaxf(fmaxf(fmaxf(v[0], v[1]), fmaxf(v[2], v[3])), v[4]);
#pragma unroll
            for (int nn = 0; nn < 7; ++nn) {
                float g = 0.f, nf = 0.f;
#pragma unroll
                for (int a = 0; a < NW; a++) {
                    float d = v[a] - tau;
                    bool fr = (d <= h[a]);
                    g += fr ? d : h[a];
                    nf += fr ? 1.f : 0.f;
                }
                tau += g / nf;
            }
#pragma unroll
            for (int a = 0; a < NW; a++) {
                z[a] = fminf(v[a] - tau, h[a]);
                zsw[n][w][a][lane] = z[a];
            }
        }
    }

    if (act) {
        float m = fmaxf(fmaxf(fmaxf(z[0], z[1]), fmaxf(z[2], z[3])), z[4]);
        if (m > 0.001f) atomicAdd(&svc, 1);
#pragma unroll
        for (int a = 0; a < NW; a++) qp3[pr * NW + a] = z[a];
    }
    __syncthreads();
    if (tid == 0) *outNumSv = (float)svc;
}

// ================= K2: W[a][d] = sum_s support[s][d] * qp3[s][a] =================
__global__ __launch_bounds__(256) void w_kernel(const float* __restrict__ support,
                                                const float* __restrict__ qp3,
                                                float* __restrict__ W) {
    __shared__ float q3[NS * NW];
    __shared__ float red[4 * 64 * NW];
    const int tid = threadIdx.x;
    for (int i = tid; i < NS * NW; i += 256) q3[i] = qp3[i];
    __syncthreads();
    const int ld = tid & 63;
    const int sq = tid >> 6;
    const int d  = blockIdx.x * 64 + ld;
    const int s0 = sq * 32;
    const int s1 = (sq == 3) ? NS : (s0 + 32);
    float acc[NW] = {0.f, 0.f, 0.f, 0.f, 0.f};
#pragma unroll 4
    for (int s = s0; s < s1; ++s) {
        float sv = support[(size_t)s * DD + d];
#pragma unroll
        for (int a = 0; a < NW; a++) acc[a] += sv * q3[s * NW + a];
    }
    float* rr = &red[tid * NW];
#pragma unroll
    for (int a = 0; a < NW; a++) rr[a] = acc[a];
    __syncthreads();
    if (sq == 0) {
#pragma unroll
        for (int a = 0; a < NW; a++) {
            float s = red[(0 * 64 + ld) * NW + a] + red[(1 * 64 + ld) * NW + a]
                    + red[(2 * 64 + ld) * NW + a] + red[(3 * 64 + ld) * NW + a];
            W[(size_t)a * DD + d] = s;
        }
    }
}

// ================= K3: logits, 4 queries/block (2 reps x 2q), query L3-warm ======
__global__ __launch_bounds__(256) void logits_kernel(const float* __restrict__ query,
                                                     const float* __restrict__ W,
                                                     const float* __restrict__ scale,
                                                     float* __restrict__ out) {
    __shared__ float red[4][2][NW];
    const int tid = threadIdx.x;
    const int wave = tid >> 6, lane = tid & 63;
    const int v0 = wave * 512;             // wave's float4 base (2048 floats)
    const float4* W4 = (const float4*)W;
    const float sc = scale[0];
    for (int rep = 0; rep < 2; ++rep) {
        __syncthreads();                   // LDS WAR vs previous rep (no-op on rep 0)
        const int q0 = blockIdx.x * 4 + rep * 2;
        float a0[NW] = {0.f,0.f,0.f,0.f,0.f};
        float a1[NW] = {0.f,0.f,0.f,0.f,0.f};
        const float4* qp0 = (const float4*)(query + (size_t)q0 * DD);
        const float4* qp1 = (const float4*)(query + (size_t)(q0 + 1) * DD);
#pragma unroll 2
        for (int it = 0; it < 8; ++it) {
            int dv = v0 + it * 64 + lane;
            float4 qv0 = qp0[dv];
            float4 qv1 = qp1[dv];
#pragma unroll
            for (int a = 0; a < NW; a++) {
                float4 wv = W4[a * (DD / 4) + dv];
                a0[a] += qv0.x*wv.x + qv0.y*wv.y + qv0.z*wv.z + qv0.w*wv.w;
                a1[a] += qv1.x*wv.x + qv1.y*wv.y + qv1.z*wv.z + qv1.w*wv.w;
            }
        }
#pragma unroll
        for (int off = 32; off; off >>= 1) {
#pragma unroll
            for (int a = 0; a < NW; a++) {
                a0[a] += __shfl_xor(a0[a], off);
                a1[a] += __shfl_xor(a1[a], off);
            }
        }
        if (lane == 0) {
#pragma unroll
            for (int a = 0; a < NW; a++) { red[wave][0][a] = a0[a]; red[wave][1][a] = a1[a]; }
        }
        __syncthreads();
        if (tid < 2 * NW) {
            const int ql = tid / NW, a = tid % NW;
            float s = red[0][ql][a] + red[1][ql][a] + red[2][ql][a] + red[3][ql][a];
            out[(q0 + ql) * NW + a] = sc * s;
        }
    }
}

extern "C" void kernel_launch(void* const* d_in, const int* in_sizes, int n_in,
                              void* d_out, int out_size, void* d_ws, size_t ws_size,
                              hipStream_t stream) {
    const float* query   = (const float*)d_in[0];
    const float* support = (const float*)d_in[1];
    const int*   labels  = (const int*)d_in[2];
    const float* scale   = (const float*)d_in[5];
    float* out = (float*)d_out;
    float* ws  = (float*)d_ws;

    float* Kg  = ws + OFF_K;
    float* qp3 = ws + OFF_QP3;
    float* W   = ws + OFF_W;

    // zero K accumulator (atomicAdd target)
    hipMemsetAsync((void*)Kg, 0, (size_t)(NS * NS) * sizeof(float), stream);

    hipLaunchKernelGGL(k1a_gram_prefetch, dim3(K1_BLKS), dim3(256), 0, stream,
                       query, support, Kg);
    hipLaunchKernelGGL(qp_solve, dim3(1), dim3(256), 0, stream, Kg, labels, qp3, out + NQ * NW);
    hipLaunchKernelGGL(w_kernel, dim3(DD / 64), dim3(256), 0, stream, support, qp3, W);
    hipLaunchKernelGGL(logits_kernel, dim3(NQ / 4), dim3(256), 0, stream, query, W, scale, out);
}

// Round 6
// 198.054 us; speedup vs baseline: 8.0866x; 1.1245x over previous
//
#include <hip/hip_runtime.h>

#define NS   125      // n_support
#define NW   5        // n_way
#define NQ   2048
#define DD   8192
#define CREG 0.1f
#define PGD_ITERS 10

// ws float offsets
#define OFF_K     1000000              // 15625 floats (K), atomically accumulated
#define OFF_QP3   1016000              // 625
#define OFF_W     1017000              // 5*8192

// ================= K1: gram, 256 blocks (64 d-chunks x 2x2 quadrants) ============
// Each block: stage a 128-d chunk of two 64-row support tiles into LDS, compute
// the 64x64 quadrant partial in registers, then ONE atomicAdd per output element
// into memset-zeroed Kg (device-scope atomics are coherent at the MALL).
__global__ __launch_bounds__(256, 2) void gram_atomic(const float* __restrict__ support,
                                                      float* __restrict__ Kg) {
    __shared__ __align__(16) float As[128][68];  // [d][s-local], pitch 68
    __shared__ __align__(16) float Bs[128][68];
    const int tid = threadIdx.x;
    const int c  = blockIdx.x >> 2;              // d-chunk 0..63
    const int qy = blockIdx.x & 1, qz = (blockIdx.x >> 1) & 1;
    const int d0 = c * 128;
    const int sy0 = qy * 64, sz0 = qz * 64;
    for (int idx = tid; idx < 64 * 128; idx += 256) {
        int sl = idx >> 7, dj = idx & 127;
        int sa = sy0 + sl, sb = sz0 + sl;
        As[dj][sl] = (sa < NS) ? support[(size_t)sa * DD + d0 + dj] : 0.f;
        Bs[dj][sl] = (sb < NS) ? support[(size_t)sb * DD + d0 + dj] : 0.f;
    }
    __syncthreads();
    const int tx = tid & 15, ty = tid >> 4;   // 4x4 tile per thread
    float acc[4][4];
#pragma unroll
    for (int i = 0; i < 4; i++)
#pragma unroll
        for (int j = 0; j < 4; j++) acc[i][j] = 0.f;
#pragma unroll 4
    for (int d = 0; d < 128; ++d) {
        float4 a = *(const float4*)&As[d][tx * 4];
        float4 b = *(const float4*)&Bs[d][ty * 4];
        float av[4] = {a.x, a.y, a.z, a.w};
        float bv[4] = {b.x, b.y, b.z, b.w};
#pragma unroll
        for (int i = 0; i < 4; i++)
#pragma unroll
            for (int j = 0; j < 4; j++) acc[i][j] += av[i] * bv[j];
    }
#pragma unroll
    for (int i = 0; i < 4; i++) {
        int gi = sy0 + tx * 4 + i;
        if (gi >= NS) continue;
#pragma unroll
        for (int j = 0; j < 4; j++) {
            int gj = sz0 + ty * 4 + j;
            if (gj < NS) atomicAdd(&Kg[gi * NS + gj], acc[i][j]);
        }
    }
}

// ================= K2: QP solve, 1 block (dispatch boundary syncs Kg) ============
__global__ __launch_bounds__(256) void qp_solve(const float* __restrict__ Kg,
                                                const int* __restrict__ labels,
                                                float* __restrict__ qp3,
                                                float* __restrict__ outNumSv) {
    __shared__ float red2[2][128 * 25];             // [parity][row*25 + w*5 + a]
    __shared__ __align__(16) float zsw[2][4][NW][32];
    __shared__ float rsx[2];
    __shared__ int   svc;

    const int tid  = threadIdx.x;
    const int w    = tid >> 6;
    const int lane = tid & 63;
    const int c0   = w * 32;
    const int r0   = lane, r1 = lane + 64;

    float kr0[32], kr1[32];
#pragma unroll
    for (int j = 0; j < 32; ++j) {
        const int col = c0 + j;
        const bool cv = (col < NS);
        kr0[j] = cv ? Kg[col * NS + r0] : 0.f;
        kr1[j] = (cv && r1 < NS) ? Kg[col * NS + r1] : 0.f;
    }
    for (int idx = tid; idx < 2 * 4 * NW * 32; idx += 256) ((float*)zsw)[idx] = 0.f;
    if (tid == 0) svc = 0;
    float rsum0 = 0.f, rsum1 = 0.f;
#pragma unroll
    for (int j = 0; j < 32; ++j) { rsum0 += fabsf(kr0[j]); rsum1 += fabsf(kr1[j]); }
    red2[0][r0 * 25 + w * 5] = rsum0;
    red2[0][r1 * 25 + w * 5] = rsum1;
    __syncthreads();
    const int prw = w * 64 + lane;
    if (w < 2) {
        const float* rr = &red2[0][prw * 25];
        float t = (prw < NS) ? rr[0] + rr[5] + rr[10] + rr[15] : 0.f;
#pragma unroll
        for (int off = 32; off; off >>= 1) t = fmaxf(t, __shfl_xor(t, off));
        if (lane == 0) rsx[w] = t;
    }
    __syncthreads();
    const float eta = 1.9f / (fmaxf(rsx[0], rsx[1]) + 1.0f);  // G = kron(K,I5)+I
    const int pr   = c0 + lane;
    const bool act = (lane < 32) && (pr < NS);
    const int lab  = act ? labels[pr] : 0;
    float z[NW] = {0.f, 0.f, 0.f, 0.f, 0.f};

    for (int it = 0; it < PGD_ITERS; ++it) {
        const int p = it & 1, n = p ^ 1;
        float acc0[NW] = {0.f, 0.f, 0.f, 0.f, 0.f};
        float acc1[NW] = {0.f, 0.f, 0.f, 0.f, 0.f};
#pragma unroll
        for (int c = 0; c < 8; ++c) {
            float4 z0 = *(const float4*)&zsw[p][w][0][4 * c];
            float4 z1 = *(const float4*)&zsw[p][w][1][4 * c];
            float4 z2 = *(const float4*)&zsw[p][w][2][4 * c];
            float4 z3 = *(const float4*)&zsw[p][w][3][4 * c];
            float4 z4 = *(const float4*)&zsw[p][w][4][4 * c];
            const float k00 = kr0[4*c], k01 = kr0[4*c+1], k02 = kr0[4*c+2], k03 = kr0[4*c+3];
            const float k10 = kr1[4*c], k11 = kr1[4*c+1], k12 = kr1[4*c+2], k13 = kr1[4*c+3];
            acc0[0] += k00*z0.x + k01*z0.y + k02*z0.z + k03*z0.w;
            acc0[1] += k00*z1.x + k01*z1.y + k02*z1.z + k03*z1.w;
            acc0[2] += k00*z2.x + k01*z2.y + k02*z2.z + k03*z2.w;
            acc0[3] += k00*z3.x + k01*z3.y + k02*z3.z + k03*z3.w;
            acc0[4] += k00*z4.x + k01*z4.y + k02*z4.z + k03*z4.w;
            acc1[0] += k10*z0.x + k11*z0.y + k12*z0.z + k13*z0.w;
            acc1[1] += k10*z1.x + k11*z1.y + k12*z1.z + k13*z1.w;
            acc1[2] += k10*z2.x + k11*z2.y + k12*z2.z + k13*z2.w;
            acc1[3] += k10*z3.x + k11*z3.y + k12*z3.z + k13*z3.w;
            acc1[4] += k10*z4.x + k11*z4.y + k12*z4.z + k13*z4.w;
        }
        {
            float* b0 = &red2[p][r0 * 25 + w * 5];
            b0[0] = acc0[0]; b0[1] = acc0[1]; b0[2] = acc0[2]; b0[3] = acc0[3]; b0[4] = acc0[4];
            float* b1 = &red2[p][r1 * 25 + w * 5];
            b1[0] = acc1[0]; b1[1] = acc1[1]; b1[2] = acc1[2]; b1[3] = acc1[3]; b1[4] = acc1[4];
        }
        __syncthreads();                       // the ONLY barrier per iteration
        if (act) {
            const float* rr = &red2[p][pr * 25];
            float v[NW], h[NW];
#pragma unroll
            for (int a = 0; a < NW; a++) {
                float kz = rr[a] + rr[5 + a] + rr[10 + a] + rr[15 + a];
                float g = kz + z[a] - ((a == lab) ? 1.f : 0.f);   // Gz + e
                v[a] = z[a] - eta * g;
                h[a] = (a == lab) ? CREG : 0.f;
            }
            float tau = fmaxf(fmaxf(fmaxf(v[0], v[1]), fmaxf(v[2], v[3])), v[4]);
#pragma unroll
            for (int nn = 0; nn < 7; ++nn) {
                float g = 0.f, nf = 0.f;
#pragma unroll
                for (int a = 0; a < NW; a++) {
                    float d = v[a] - tau;
                    bool fr = (d <= h[a]);
                    g += fr ? d : h[a];
                    nf += fr ? 1.f : 0.f;
                }
                tau += g / nf;
            }
#pragma unroll
            for (int a = 0; a < NW; a++) {
                z[a] = fminf(v[a] - tau, h[a]);
                zsw[n][w][a][lane] = z[a];
            }
        }
    }

    if (act) {
        float m = fmaxf(fmaxf(fmaxf(z[0], z[1]), fmaxf(z[2], z[3])), z[4]);
        if (m > 0.001f) atomicAdd(&svc, 1);
#pragma unroll
        for (int a = 0; a < NW; a++) qp3[pr * NW + a] = z[a];
    }
    __syncthreads();
    if (tid == 0) *outNumSv = (float)svc;
}

// ================= K3: W[a][d] = sum_s support[s][d] * qp3[s][a] =================
__global__ __launch_bounds__(256) void w_kernel(const float* __restrict__ support,
                                                const float* __restrict__ qp3,
                                                float* __restrict__ W) {
    __shared__ float q3[NS * NW];
    __shared__ float red[4 * 64 * NW];
    const int tid = threadIdx.x;
    for (int i = tid; i < NS * NW; i += 256) q3[i] = qp3[i];
    __syncthreads();
    const int ld = tid & 63;
    const int sq = tid >> 6;
    const int d  = blockIdx.x * 64 + ld;
    const int s0 = sq * 32;
    const int s1 = (sq == 3) ? NS : (s0 + 32);
    float acc[NW] = {0.f, 0.f, 0.f, 0.f, 0.f};
#pragma unroll 4
    for (int s = s0; s < s1; ++s) {
        float sv = support[(size_t)s * DD + d];
#pragma unroll
        for (int a = 0; a < NW; a++) acc[a] += sv * q3[s * NW + a];
    }
    float* rr = &red[tid * NW];
#pragma unroll
    for (int a = 0; a < NW; a++) rr[a] = acc[a];
    __syncthreads();
    if (sq == 0) {
#pragma unroll
        for (int a = 0; a < NW; a++) {
            float s = red[(0 * 64 + ld) * NW + a] + red[(1 * 64 + ld) * NW + a]
                    + red[(2 * 64 + ld) * NW + a] + red[(3 * 64 + ld) * NW + a];
            W[(size_t)a * DD + d] = s;
        }
    }
}

// ================= K4: logits, 4 queries/block (2 reps x 2q) =====================
__global__ __launch_bounds__(256) void logits_kernel(const float* __restrict__ query,
                                                     const float* __restrict__ W,
                                                     const float* __restrict__ scale,
                                                     float* __restrict__ out) {
    __shared__ float red[4][2][NW];
    const int tid = threadIdx.x;
    const int wave = tid >> 6, lane = tid & 63;
    const int v0 = wave * 512;             // wave's float4 base (2048 floats)
    const float4* W4 = (const float4*)W;
    const float sc = scale[0];
    for (int rep = 0; rep < 2; ++rep) {
        __syncthreads();                   // LDS WAR vs previous rep (no-op on rep 0)
        const int q0 = blockIdx.x * 4 + rep * 2;
        float a0[NW] = {0.f,0.f,0.f,0.f,0.f};
        float a1[NW] = {0.f,0.f,0.f,0.f,0.f};
        const float4* qp0 = (const float4*)(query + (size_t)q0 * DD);
        const float4* qp1 = (const float4*)(query + (size_t)(q0 + 1) * DD);
#pragma unroll 2
        for (int it = 0; it < 8; ++it) {
            int dv = v0 + it * 64 + lane;
            float4 qv0 = qp0[dv];
            float4 qv1 = qp1[dv];
#pragma unroll
            for (int a = 0; a < NW; a++) {
                float4 wv = W4[a * (DD / 4) + dv];
                a0[a] += qv0.x*wv.x + qv0.y*wv.y + qv0.z*wv.z + qv0.w*wv.w;
                a1[a] += qv1.x*wv.x + qv1.y*wv.y + qv1.z*wv.z + qv1.w*wv.w;
            }
        }
#pragma unroll
        for (int off = 32; off; off >>= 1) {
#pragma unroll
            for (int a = 0; a < NW; a++) {
                a0[a] += __shfl_xor(a0[a], off);
                a1[a] += __shfl_xor(a1[a], off);
            }
        }
        if (lane == 0) {
#pragma unroll
            for (int a = 0; a < NW; a++) { red[wave][0][a] = a0[a]; red[wave][1][a] = a1[a]; }
        }
        __syncthreads();
        if (tid < 2 * NW) {
            const int ql = tid / NW, a = tid % NW;
            float s = red[0][ql][a] + red[1][ql][a] + red[2][ql][a] + red[3][ql][a];
            out[(q0 + ql) * NW + a] = sc * s;
        }
    }
}

extern "C" void kernel_launch(void* const* d_in, const int* in_sizes, int n_in,
                              void* d_out, int out_size, void* d_ws, size_t ws_size,
                              hipStream_t stream) {
    const float* query   = (const float*)d_in[0];
    const float* support = (const float*)d_in[1];
    const int*   labels  = (const int*)d_in[2];
    const float* scale   = (const float*)d_in[5];
    float* out = (float*)d_out;
    float* ws  = (float*)d_ws;

    float* Kg  = ws + OFF_K;
    float* qp3 = ws + OFF_QP3;
    float* W   = ws + OFF_W;

    // zero K accumulator (atomicAdd target)
    hipMemsetAsync((void*)Kg, 0, (size_t)(NS * NS) * sizeof(float), stream);

    hipLaunchKernelGGL(gram_atomic, dim3(256), dim3(256), 0, stream, support, Kg);
    hipLaunchKernelGGL(qp_solve, dim3(1), dim3(256), 0, stream, Kg, labels, qp3, out + NQ * NW);
    hipLaunchKernelGGL(w_kernel, dim3(DD / 64), dim3(256), 0, stream, support, qp3, W);
    hipLaunchKernelGGL(logits_kernel, dim3(NQ / 4), dim3(256), 0, stream, query, W, scale, out);
}